// Round 6
// baseline (454.582 us; speedup 1.0000x reference)
//
#include <hip/hip_runtime.h>
#include <hip/hip_bf16.h>
#include <hip/hip_fp16.h>

// Problem constants (from setup_inputs): B=4, T=4096, D=1024, H=1024
#define B_ 4
#define T_ 4096
#define D_ 1024
#define H_ 1024
#define M_ (B_ * T_)   // 16384

typedef __attribute__((ext_vector_type(8))) short short8;   // 8 bf16 = 4 VGPRs (MFMA A/B frag)
typedef __attribute__((ext_vector_type(4))) float f32x4;    // MFMA C/D frag

// ---------------- fp32 -> bf16 (RNE) ----------------
__device__ __forceinline__ unsigned short f2bf(float f) {
    unsigned int u = __float_as_uint(f);
    u += 0x7fffu + ((u >> 16) & 1u);
    return (unsigned short)(u >> 16);
}

// One kernel converts x, Wz, Wh (ranges concatenated).
__global__ __launch_bounds__(256) void convert_all(
    const float* __restrict__ x, const float* __restrict__ wz, const float* __restrict__ wh,
    unsigned short* __restrict__ xb, unsigned short* __restrict__ wzb, unsigned short* __restrict__ whb)
{
    int i = blockIdx.x * 256 + threadIdx.x;
    const float* s; unsigned short* d; int off;
    if (i < 4194304)      { s = x;  d = xb;  off = i; }
    else if (i < 4456448) { s = wz; d = wzb; off = i - 4194304; }
    else                  { s = wh; d = whb; off = i - 4456448; }
    float4 f = ((const float4*)s)[off];
    ushort4 u;
    u.x = f2bf(f.x); u.y = f2bf(f.y); u.z = f2bf(f.z); u.w = f2bf(f.w);
    ((ushort4*)d)[off] = u;
}

// async global->LDS, 16B per lane; LDS dest = wave-uniform base + lane*16
__device__ __forceinline__ void async16(const void* g, void* l) {
    __builtin_amdgcn_global_load_lds(
        (__attribute__((address_space(1))) void*)g,
        (__attribute__((address_space(3))) void*)l,
        16, 0, 0);
}

// ---------------- fused dual GEMM + epilogue + chunk-summary ----------------
// Tile 256(M) x 64(N)-dual, 512 threads (8 waves), BK=32, DOUBLE-BUFFERED LDS,
// ONE barrier per K-step: stage(next buf) issued before compute(cur buf), so the
// compiler's vmcnt(0) drain (at the NEXT barrier) overlaps a full compute phase.
// Wave w: mq = w>>1 (64 rows = one full scan chunk), nh = w&1 (32 of the 64 cols), both matrices.
// Per wave per K-step: 8 ds_read_b128 + 16 MFMA; staging 3 async16/thread (A 16 KB + Bz 4 + Bh 4).
// LDS slots (per buffer, fragment-order subtiles of 16 rows x 32 k, 1 KB each):
//   0..15 = A row-groups, 16..19 = Bz, 20..23 = Bh  -> stage slot for wave w: A {2w,2w+1}, B {16+w}.
__global__ __launch_bounds__(512, 6) void dual_gemm_kernel(
    const unsigned short* __restrict__ xb,   // [M][D] bf16
    const unsigned short* __restrict__ wzb,  // [H][D] bf16
    const unsigned short* __restrict__ whb,  // [H][D] bf16
    const float* __restrict__ bz,
    const float* __restrict__ bh,
    __half2* __restrict__ av16,              // [M][H] half2(a,v)
    float2* __restrict__ chunkAV)            // [64][B][H]
{
    __shared__ short8 lds[2][24 * 64];       // 2 x 24 KB

    const int tid  = threadIdx.x;
    const int lane = tid & 63;
    const int w    = __builtin_amdgcn_readfirstlane(tid >> 6);  // 0..7, SGPR
    const int mq   = w >> 1;                 // 0..3: 64-row group (= chunk)
    const int nh   = w & 1;                  // 0..1: 32-col half
    const int mb   = blockIdx.x >> 4;        // 0..63  (mb-major: A-sharing blocks adjacent)
    const int nb   = blockIdx.x & 15;        // 0..15
    const int r16  = lane & 15;
    const int q    = lane >> 4;

    const int laneoff = r16 * D_ + q * 8;
    // staging sources (wave-uniform base + shared lane offset)
    const unsigned short* gA0 = xb + (size_t)(mb * 256 + (2 * w) * 16) * D_ + laneoff;
    const unsigned short* gA1 = gA0 + 16 * D_;
    const unsigned short* gB  = (w < 4)
        ? wzb + (size_t)(nb * 64 + w * 16) * D_ + laneoff
        : whb + (size_t)(nb * 64 + (w - 4) * 16) * D_ + laneoff;

    f32x4 accz[4][2] = {};
    f32x4 acch[4][2] = {};

#define STAGE(b, koff) do {                                   \
    async16(gA0 + (koff), &lds[b][(2 * w) * 64]);             \
    async16(gA1 + (koff), &lds[b][(2 * w + 1) * 64]);         \
    async16(gB  + (koff), &lds[b][(16 + w) * 64]);            \
    } while (0)

#define COMPUTE(b) do {                                                          \
    short8 fa[4], fz[2], fh[2];                                                  \
    _Pragma("unroll") for (int gm = 0; gm < 4; ++gm)                             \
        fa[gm] = lds[b][(4 * mq + gm) * 64 + lane];                              \
    _Pragma("unroll") for (int gn = 0; gn < 2; ++gn) {                           \
        fz[gn] = lds[b][(16 + 2 * nh + gn) * 64 + lane];                         \
        fh[gn] = lds[b][(20 + 2 * nh + gn) * 64 + lane];                         \
    }                                                                            \
    _Pragma("unroll") for (int gm = 0; gm < 4; ++gm)                             \
    _Pragma("unroll") for (int gn = 0; gn < 2; ++gn) {                           \
        accz[gm][gn] = __builtin_amdgcn_mfma_f32_16x16x32_bf16(fa[gm], fz[gn], accz[gm][gn], 0, 0, 0); \
        acch[gm][gn] = __builtin_amdgcn_mfma_f32_16x16x32_bf16(fa[gm], fh[gn], acch[gm][gn], 0, 0, 0); \
    } } while (0)

    STAGE(0, 0);
    int kk = 0;
#pragma unroll 1
    for (; kk < D_ - 64; kk += 64) {
        __syncthreads();                     // drains stage->buf0 (issued last iter); WAR for buf1 reads
        STAGE(1, kk + 32);                   // DMA into buf1 overlaps compute of buf0
        COMPUTE(0);
        __syncthreads();                     // drains stage->buf1; WAR for buf0 reads
        STAGE(0, kk + 64);
        COMPUTE(1);
    }
    // tail: kk = D_-64 = 960
    __syncthreads();
    STAGE(1, kk + 32);
    COMPUTE(0);
    __syncthreads();
    COMPUTE(1);
#undef STAGE
#undef COMPUTE

    // Epilogue. C/D layout: col = lane&15, row = q*4 + rr  [verified m89/m91]
    const int cglob = mb * 4 + mq;           // global 64-row chunk id, 0..255
    const int cc = cglob & 63;
    const int bb = cglob >> 6;
#pragma unroll
    for (int gn = 0; gn < 2; ++gn) {
        const int ncol = nb * 64 + nh * 32 + gn * 16 + r16;
        const float bzv = bz[ncol];
        const float bhv = bh[ncol];
        float CA = 1.0f, CV = 0.0f;          // chunk composite
#pragma unroll
        for (int gm = 0; gm < 4; ++gm) {
            float LA = 1.0f, LV = 0.0f;      // this lane's 4-row segment
#pragma unroll
            for (int rr = 0; rr < 4; ++rr) {
                float kv = accz[gm][gn][rr] + bzv;
                float hv = acch[gm][gn][rr] + bhv;
                float tk = __expf(-fabsf(kv));
                float ik = 1.0f / (1.0f + tk);
                float sig = (kv >= 0.0f) ? ik : tk * ik;         // sigmoid(k)
                float ac  = (kv >= 0.0f) ? tk * ik : ik;         // sigmoid(-k)
                float th = __expf(-fabsf(hv));
                float ih = 1.0f / (1.0f + th);
                float gh = (hv >= 0.0f) ? (hv + 0.5f) : th * ih; // g(hb)
                float vv = sig * gh;
                const size_t m = (size_t)mb * 256 + mq * 64 + gm * 16 + q * 4 + rr;
                av16[(size_t)m * H_ + ncol] = __floats2half2_rn(ac, vv);
                LV = ac * LV + vv;           // ascending t composition
                LA = ac * LA;
            }
            // order-preserving combine across q (lower lane index = earlier segment)
#pragma unroll
            for (int mask = 16; mask <= 32; mask <<= 1) {
                float PA = __shfl_xor(LA, mask);
                float PV = __shfl_xor(LV, mask);
                if (lane & mask) { LV = LA * PV + LV; LA = LA * PA; }
                else             { LV = PA * LV + PV; LA = PA * LA; }
            }
            CV = LA * CV + LV;
            CA = LA * CA;
        }
        if (q == 0)
            chunkAV[cc * 4096 + bb * 1024 + ncol] = make_float2(CA, CV);
    }
}

// ---------------- scan pass2: sequential over 64 chunk summaries per channel ----------------
__global__ __launch_bounds__(256) void scan_pass2(const float2* __restrict__ chunkAV,
                                                  const float* __restrict__ h0,
                                                  float* __restrict__ hstart) {
    int chan = blockIdx.x * blockDim.x + threadIdx.x;   // 4096 threads
    int n = chan & (H_ - 1);
    int b = chan >> 10;
    float x = h0[b * H_ + n];
    float h;
    if (x >= 0.0f) { h = x + 0.5f; }
    else { float t = __expf(x); h = t / (1.0f + t); }   // g(h0)
#pragma unroll 8
    for (int c = 0; c < 64; ++c) {
        hstart[c * 4096 + chan] = h;
        float2 s = chunkAV[c * 4096 + chan];
        h = s.x * h + s.y;
    }
}

// ---------------- scan pass3: replay each chunk from entry state ----------------
__global__ __launch_bounds__(256) void scan_pass3(const __half2* __restrict__ av16,
                                                  const float* __restrict__ hstart,
                                                  float* __restrict__ out) {
    int g = blockIdx.x * blockDim.x + threadIdx.x;
    int n = g & (H_ - 1);
    int rest = g >> 10;
    int c = rest & 63;
    int b = rest >> 6;
    float h = hstart[c * 4096 + b * 1024 + n];
    const __half2* base = av16 + ((size_t)(b * T_ + c * 64)) * H_ + n;
    float* obase = out + ((size_t)(b * T_ + c * 64)) * H_ + n;
#pragma unroll 8
    for (int t = 0; t < 64; ++t) {
        float2 p = __half22float2(base[(size_t)t * H_]);
        h = p.x * h + p.y;
        obase[(size_t)t * H_] = h;
    }
}

// ---------------- launch ----------------
extern "C" void kernel_launch(void* const* d_in, const int* in_sizes, int n_in,
                              void* d_out, int out_size, void* d_ws, size_t ws_size,
                              hipStream_t stream) {
    const float* x  = (const float*)d_in[0];   // [B,T,D]
    const float* h0 = (const float*)d_in[1];   // [B,H]
    const float* Wz = (const float*)d_in[2];   // [H,D]
    const float* bz = (const float*)d_in[3];   // [H]
    const float* Wh = (const float*)d_in[4];   // [H,D]
    const float* bh = (const float*)d_in[5];   // [H]
    float* out = (float*)d_out;

    // workspace layout (bytes):
    //   xb  bf16 [M][D]            @ 0            33,554,432
    //   wzb bf16 [H][D]            @ 33554432      2,097,152
    //   whb bf16 [H][D]            @ 35651584      2,097,152
    //   av16 half2 [M][H]          @ 37748736     67,108,864
    //   chunkAV float2 [64][B][H]  @ 104857600     2,097,152
    //   hstart fp32 [64][B*H]      @ 106954752     1,048,576
    char* ws = (char*)d_ws;
    unsigned short* xb  = (unsigned short*)(ws);
    unsigned short* wzb = (unsigned short*)(ws + 33554432);
    unsigned short* whb = (unsigned short*)(ws + 35651584);
    __half2* av16       = (__half2*)(ws + 37748736);
    float2* chunkAV     = (float2*)(ws + 104857600);
    float*  hstart      = (float*)(ws + 106954752);

    convert_all<<<18432, 256, 0, stream>>>(x, Wz, Wh, xb, wzb, whb);

    dual_gemm_kernel<<<1024, 512, 0, stream>>>(xb, wzb, whb, bz, bh, av16, chunkAV);

    scan_pass2<<<16,   256, 0, stream>>>(chunkAV, h0, hstart);
    scan_pass3<<<1024, 256, 0, stream>>>(av16, hstart, out);
}